// Round 1
// baseline (26.051 us; speedup 1.0000x reference)
//
#include <hip/hip_runtime.h>

// Cond_PlanarTrans: out = s + u * tanh(w*s + b)
//  where w = relu(o*W1[n] + b1[n]), u = relu(o*W2[n] + b2[n]),
//        b = relu(o*W3[n] + b3[n]),  n = m[b,p]  (N_M=8, O_DIM=1)
// Purely elementwise over B*P = 8,388,608 elements -> memory-bound.
// Traffic: 16 B/elem (m,s,o in; out) = 134 MB -> ~21 us floor at 6.3 TB/s.

__global__ __launch_bounds__(256) void cond_planar_kernel(
    const int4* __restrict__ m4,
    const float4* __restrict__ s4,
    const float4* __restrict__ o4,
    const float* __restrict__ W1, const float* __restrict__ b1,
    const float* __restrict__ W2, const float* __restrict__ b2,
    const float* __restrict__ W3, const float* __restrict__ b3,
    float4* __restrict__ out4,
    int n4)
{
    // Stage the 6 x 8 = 48 weight scalars in LDS (one load per block).
    __shared__ float wts[48];
    int t = threadIdx.x;
    if (t < 8) {
        wts[t]      = W1[t];
        wts[8 + t]  = b1[t];
        wts[16 + t] = W2[t];
        wts[24 + t] = b2[t];
        wts[32 + t] = W3[t];
        wts[40 + t] = b3[t];
    }
    __syncthreads();

    int idx    = blockIdx.x * blockDim.x + t;
    int stride = gridDim.x * blockDim.x;

    for (int i = idx; i < n4; i += stride) {
        int4   mv = m4[i];
        float4 sv = s4[i];
        float4 ov = o4[i];

        int   mi[4] = { mv.x, mv.y, mv.z, mv.w };
        float ss[4] = { sv.x, sv.y, sv.z, sv.w };
        float oo[4] = { ov.x, ov.y, ov.z, ov.w };
        float r[4];

#pragma unroll
        for (int j = 0; j < 4; ++j) {
            int n = mi[j] & 7;  // m in [0,8); mask guards poison without changing valid inputs
            float w  = fmaxf(fmaf(oo[j], wts[n],      wts[8 + n]),  0.0f);
            float u  = fmaxf(fmaf(oo[j], wts[16 + n], wts[24 + n]), 0.0f);
            float bb = fmaxf(fmaf(oo[j], wts[32 + n], wts[40 + n]), 0.0f);
            r[j] = fmaf(u, tanhf(fmaf(w, ss[j], bb)), ss[j]);
        }

        out4[i] = make_float4(r[0], r[1], r[2], r[3]);
    }
}

extern "C" void kernel_launch(void* const* d_in, const int* in_sizes, int n_in,
                              void* d_out, int out_size, void* d_ws, size_t ws_size,
                              hipStream_t stream)
{
    const int*   m  = (const int*)d_in[0];
    const float* s  = (const float*)d_in[1];
    const float* o  = (const float*)d_in[2];
    const float* W1 = (const float*)d_in[3];
    const float* b1 = (const float*)d_in[4];
    const float* W2 = (const float*)d_in[5];
    const float* b2 = (const float*)d_in[6];
    const float* W3 = (const float*)d_in[7];
    const float* b3 = (const float*)d_in[8];
    float* out = (float*)d_out;

    int n  = out_size;        // B*P*O_DIM = 8,388,608 (divisible by 4)
    int n4 = n / 4;

    const int block = 256;
    int grid = (n4 + block - 1) / block;
    if (grid > 2048) grid = 2048;   // 8 blocks/CU on 256 CUs; grid-stride covers rest

    cond_planar_kernel<<<grid, block, 0, stream>>>(
        (const int4*)m, (const float4*)s, (const float4*)o,
        W1, b1, W2, b2, W3, b3,
        (float4*)out, n4);
}

// Round 3
// 25.532 us; speedup vs baseline: 1.0203x; 1.0203x over previous
//
#include <hip/hip_runtime.h>

// Cond_PlanarTrans: out = s + u * tanh(w*s + b)
//  w = relu(o*W1[n]+b1[n]), u = relu(o*W2[n]+b2[n]), b = relu(o*W3[n]+b3[n])
//  n = m[b,p]; N_M=8, O_DIM=1 -> pure elementwise over 8,388,608 floats.
// Memory-bound: 16 B/elem = 134 MB -> ~21.3 us floor at 6.3 TB/s copy ceiling.
// R2: NO nontemporal stores (R1 post-timing divergence: nt store + poison
//     memset left stale L2 lines for the readback). 4 float4 chunks/thread,
//     all 12 loads issued before any wait; fast branchless tanh.

typedef float f32x4 __attribute__((ext_vector_type(4)));

__device__ __forceinline__ float fast_tanh(float x) {
    // tanh(x) = 1 - 2/(exp(2x)+1); exp2 form. Exact at saturation, no branches.
    float e = __builtin_amdgcn_exp2f(x * 2.88539008177793f);
    return fmaf(-2.0f, __builtin_amdgcn_rcpf(e + 1.0f), 1.0f);
}

#define CHUNKS 4

__global__ __launch_bounds__(256) void cond_planar_kernel(
    const int4* __restrict__ m4,
    const float4* __restrict__ s4,
    const float4* __restrict__ o4,
    const float* __restrict__ W1, const float* __restrict__ b1,
    const float* __restrict__ W2, const float* __restrict__ b2,
    const float* __restrict__ W3, const float* __restrict__ b3,
    float4* __restrict__ out4,
    int n4, int stride)
{
    __shared__ float wts[48];
    int t = threadIdx.x;
    if (t < 8) {
        wts[t]      = W1[t];
        wts[8 + t]  = b1[t];
        wts[16 + t] = W2[t];
        wts[24 + t] = b2[t];
        wts[32 + t] = W3[t];
        wts[40 + t] = b3[t];
    }
    __syncthreads();

    int i0 = blockIdx.x * blockDim.x + t;

    int  idx[CHUNKS];
    bool val[CHUNKS];
    int4   mv[CHUNKS];
    float4 sv[CHUNKS];
    float4 ov[CHUNKS];

#pragma unroll
    for (int c = 0; c < CHUNKS; ++c) {
        idx[c] = i0 + c * stride;
        val[c] = idx[c] < n4;
    }
    // Issue all loads up front; independent -> 12 loads in flight per thread.
#pragma unroll
    for (int c = 0; c < CHUNKS; ++c) {
        if (val[c]) { mv[c] = m4[idx[c]]; sv[c] = s4[idx[c]]; ov[c] = o4[idx[c]]; }
    }

#pragma unroll
    for (int c = 0; c < CHUNKS; ++c) {
        if (!val[c]) continue;
        int   mi[4] = { mv[c].x, mv[c].y, mv[c].z, mv[c].w };
        float ss[4] = { sv[c].x, sv[c].y, sv[c].z, sv[c].w };
        float oo[4] = { ov[c].x, ov[c].y, ov[c].z, ov[c].w };
        float r[4];
#pragma unroll
        for (int j = 0; j < 4; ++j) {
            int n = mi[j] & 7;
            float w  = fmaxf(fmaf(oo[j], wts[n],      wts[8 + n]),  0.0f);
            float u  = fmaxf(fmaf(oo[j], wts[16 + n], wts[24 + n]), 0.0f);
            float bb = fmaxf(fmaf(oo[j], wts[32 + n], wts[40 + n]), 0.0f);
            r[j] = fmaf(u, fast_tanh(fmaf(w, ss[j], bb)), ss[j]);
        }
        out4[idx[c]] = make_float4(r[0], r[1], r[2], r[3]);
    }
}

extern "C" void kernel_launch(void* const* d_in, const int* in_sizes, int n_in,
                              void* d_out, int out_size, void* d_ws, size_t ws_size,
                              hipStream_t stream)
{
    const int*   m  = (const int*)d_in[0];
    const float* s  = (const float*)d_in[1];
    const float* o  = (const float*)d_in[2];
    const float* W1 = (const float*)d_in[3];
    const float* b1 = (const float*)d_in[4];
    const float* W2 = (const float*)d_in[5];
    const float* b2 = (const float*)d_in[6];
    const float* W3 = (const float*)d_in[7];
    const float* b3 = (const float*)d_in[8];
    float* out = (float*)d_out;

    int n  = out_size;     // 8,388,608 (divisible by 4)
    int n4 = n / 4;        // 2,097,152 float4 elements

    const int block = 256;
    // Each thread handles CHUNKS float4s at distance `stride`; exact cover.
    int grid   = (n4 + CHUNKS * block - 1) / (CHUNKS * block);   // 2048 for n4 = 2M
    int stride = grid * block;

    cond_planar_kernel<<<grid, block, 0, stream>>>(
        (const int4*)m, (const float4*)s, (const float4*)o,
        W1, b1, W2, b2, W3, b3,
        (float4*)out, n4, stride);
}